// Round 3
// baseline (1676.070 us; speedup 1.0000x reference)
//
#include <hip/hip_runtime.h>
#include <hip/hip_bf16.h>

// TRANSNET on MI355X. Shapes: V=50000 D=64 F=100 K=3 L=256 R=10 ID=32 B=128.
// Float dtype (bf16 vs f32) is DETECTED on device from user_emb bit patterns;
// all float loads/stores go through flag-dispatched helpers.
// Outputs: src[128*32] then tl[128*32] in d_out (element type per flag).

#define C_V 50000
#define C_D 64
#define C_F 100
#define C_K 3
#define C_L 256
#define C_R 10
#define C_ID 32
#define C_B 128

typedef unsigned int u32;
typedef unsigned short u16;

__device__ __forceinline__ float bf2f(u16 h) { union {u32 u; float f;} v; v.u = ((u32)h) << 16; return v.f; }
__device__ __forceinline__ u16 f2bf(float f) {
    union {float f; u32 u;} v; v.f = f;
    u32 u = v.u;
    return (u16)((u + 0x7fffu + ((u >> 16) & 1u)) >> 16);  // RNE
}
__device__ __forceinline__ float ldf(const void* p, int idx, int isf) {
    return isf ? ((const float*)p)[idx] : bf2f(((const u16*)p)[idx]);
}
__device__ __forceinline__ void stf(void* p, int idx, float v, int isf) {
    if (isf) ((float*)p)[idx] = v; else ((u16*)p)[idx] = f2bf(v);
}

// ---------------------------------------------------------------------------
// K-1: classify float layout. bf16-pairs -> low u16 exponent in [0x70,0x7F]
// (values ~N(0,0.1)); f32 -> those bits are mantissa noise (hit rate 1/16).
// flag: 0 = bf16, 1 = f32.
// ---------------------------------------------------------------------------
__global__ void detect_dtype(const u32* __restrict__ ue, int* __restrict__ flag) {
    int t = threadIdx.x;                 // 64 threads
    u32 w = ue[t];
    u32 e = (w >> 7) & 0xFFu;            // low half-word's bf16 exponent field
    int hit = (e >= 0x70u && e <= 0x7Fu);
    unsigned long long m = __ballot(hit);
    if (t == 0) flag[0] = (__popcll(m) >= 32) ? 0 : 1;
}

// ---------------------------------------------------------------------------
// K0: conv weights -> fp32, layout [set][f][k][d]. Source layout [f][d][k].
// ---------------------------------------------------------------------------
__global__ __launch_bounds__(256) void prep_weights(
    const void* __restrict__ cu_Wc, const void* __restrict__ ci_Wc,
    const void* __restrict__ tc_Wc, const int* __restrict__ flag,
    float* __restrict__ wf)
{
    int id = blockIdx.x * 256 + threadIdx.x;   // 57600 = 225*256 exactly
    int isf = flag[0];
    int set = id / (C_F * C_K * C_D);
    int r   = id % (C_F * C_K * C_D);
    int f   = r / (C_K * C_D);
    int rr  = r % (C_K * C_D);
    int k   = rr / C_D;
    int d   = rr % C_D;
    const void* Wc = (set == 0) ? cu_Wc : (set == 1) ? ci_Wc : tc_Wc;
    wf[id] = ldf(Wc, (f * C_D + d) * C_K + k, isf);
}

// ---------------------------------------------------------------------------
// K2: one block per review (2688). embed-gather -> LDS(f32) -> conv1d+bias+
// relu+maxpool(L) -> linear(F->ID)+tanh, fused.
// LDS rows stride 68 words: 68*4=272 ≡ 0 mod 16 -> aligned ds_read_b128.
// ---------------------------------------------------------------------------
__global__ __launch_bounds__(256) void cnn_kernel(
    const int* __restrict__ user_reviews, const int* __restrict__ item_reviews,
    const int* __restrict__ uids, const int* __restrict__ iids,
    const int* __restrict__ user2item, const int* __restrict__ item2user,
    const int* __restrict__ rand_reviews,
    const void* __restrict__ user_emb, const void* __restrict__ item_emb,
    const void* __restrict__ te_emb,
    const void* __restrict__ cu_bc, const void* __restrict__ cu_Wl, const void* __restrict__ cu_bl,
    const void* __restrict__ ci_bc, const void* __restrict__ ci_Wl, const void* __restrict__ ci_bl,
    const void* __restrict__ tc_bc, const void* __restrict__ tc_Wl, const void* __restrict__ tc_bl,
    const int* __restrict__ flag, const float* __restrict__ wf_all,
    float* __restrict__ ws_cat, void* __restrict__ d_out)
{
    __shared__ float embf_s[258 * 68];   // row = position+1 (rows 0,257 = zero pad)
    __shared__ float bc_s[C_F];
    __shared__ float pool_w[C_F * 4];
    __shared__ float pool_f[C_F];

    const int tid = threadIdx.x;
    const int idx = blockIdx.x;
    const int isf = flag[0];

    const int* toks;
    const void* emb;
    const float* wf;
    const void *bc, *Wl, *bl;

    if (idx < C_B * C_R) {                         // user reviews
        toks = user_reviews + idx * C_L;
        emb = user_emb; wf = wf_all;
        bc = cu_bc; Wl = cu_Wl; bl = cu_bl;
    } else if (idx < 2 * C_B * C_R) {              // item reviews
        int j = idx - C_B * C_R;
        toks = item_reviews + j * C_L;
        emb = item_emb; wf = wf_all + C_F * C_K * C_D;
        bc = ci_bc; Wl = ci_Wl; bl = ci_bl;
    } else {                                       // target review (selected)
        int b = idx - 2 * C_B * C_R;
        const int* t_ = rand_reviews + b * C_L;
        int iid = iids[b];
        int uid = uids[b];
        int fu = -1, fi = -1;
        for (int r = C_R - 1; r >= 0; --r) {       // first match (argmax of bool)
            if (user2item[b * C_R + r] == iid) fu = r;
            if (item2user[b * C_R + r] == uid) fi = r;
        }
        if (fu >= 0)      t_ = user_reviews + (b * C_R + fu) * C_L;
        else if (fi >= 0) t_ = item_reviews + (b * C_R + fi) * C_L;
        toks = t_;
        emb = te_emb; wf = wf_all + 2 * C_F * C_K * C_D;
        bc = tc_bc; Wl = tc_Wl; bl = tc_bl;
    }

    // zero pad rows (positions -1 and 256); load conv bias
    if (tid < 64)                  embf_s[tid] = 0.f;
    else if (tid < 128)            embf_s[257 * 68 + (tid - 64)] = 0.f;
    else if (tid < 128 + C_F)      bc_s[tid - 128] = ldf(bc, tid - 128, isf);

    // stage this thread's token embedding row (64 f32 into LDS)
    {
        int token = toks[tid];
        float* dst = embf_s + (tid + 1) * 68;
        if (isf) {
            const float4* src = reinterpret_cast<const float4*>(
                (const float*)emb + (size_t)token * C_D);
            #pragma unroll
            for (int j = 0; j < 16; ++j) {
                float4 v = src[j];
                dst[j * 4 + 0] = v.x; dst[j * 4 + 1] = v.y;
                dst[j * 4 + 2] = v.z; dst[j * 4 + 3] = v.w;
            }
        } else {
            const uint4* src = reinterpret_cast<const uint4*>(
                (const u16*)emb + (size_t)token * C_D);
            #pragma unroll
            for (int j = 0; j < 8; ++j) {
                uint4 v = src[j];
                u32 w[4] = {v.x, v.y, v.z, v.w};
                #pragma unroll
                for (int q = 0; q < 4; ++q) {
                    dst[j * 8 + q * 2 + 0] = bf2f((u16)(w[q] & 0xFFFFu));
                    dst[j * 8 + q * 2 + 1] = bf2f((u16)(w[q] >> 16));
                }
            }
        }
    }
    __syncthreads();

    const float* r0 = embf_s + tid * 68;        // position tid-1 (k=0)
    const float* r1 = r0 + 68;                  // position tid   (k=1)
    const float* r2 = r1 + 68;                  // position tid+1 (k=2)
    const int lane = tid & 63;
    const int wave = tid >> 6;

    for (int fc = 0; fc < 25; ++fc) {
        float a0 = 0.f, a1 = 0.f, a2 = 0.f, a3 = 0.f;
        #pragma unroll
        for (int k = 0; k < 3; ++k) {
            const float* e = (k == 0) ? r0 : (k == 1) ? r1 : r2;
            const float* wb = wf + ((fc * 4) * 3 + k) * C_D;  // filter fc*4+j at +j*3*64
            #pragma unroll
            for (int p = 0; p < 16; ++p) {
                float4 x  = *reinterpret_cast<const float4*>(e + 4 * p);
                float4 wa = *reinterpret_cast<const float4*>(wb + 0 * 192 + 4 * p);
                float4 wbv= *reinterpret_cast<const float4*>(wb + 1 * 192 + 4 * p);
                float4 wc = *reinterpret_cast<const float4*>(wb + 2 * 192 + 4 * p);
                float4 wd = *reinterpret_cast<const float4*>(wb + 3 * 192 + 4 * p);
                a0 += x.x * wa.x + x.y * wa.y + x.z * wa.z + x.w * wa.w;
                a1 += x.x * wbv.x + x.y * wbv.y + x.z * wbv.z + x.w * wbv.w;
                a2 += x.x * wc.x + x.y * wc.y + x.z * wc.z + x.w * wc.w;
                a3 += x.x * wd.x + x.y * wd.y + x.z * wd.z + x.w * wd.w;
            }
        }
        #pragma unroll
        for (int j = 0; j < 4; ++j) {
            int f = fc * 4 + j;
            float v = (j == 0) ? a0 : (j == 1) ? a1 : (j == 2) ? a2 : a3;
            v = fmaxf(v + bc_s[f], 0.f);
            #pragma unroll
            for (int off = 32; off > 0; off >>= 1)
                v = fmaxf(v, __shfl_xor(v, off));
            if (lane == 0) pool_w[f * 4 + wave] = v;
        }
    }
    __syncthreads();
    if (tid < C_F) {
        pool_f[tid] = fmaxf(fmaxf(pool_w[tid * 4 + 0], pool_w[tid * 4 + 1]),
                            fmaxf(pool_w[tid * 4 + 2], pool_w[tid * 4 + 3]));
    }
    __syncthreads();
    if (tid < C_ID) {
        float s = ldf(bl, tid, isf);
        for (int f = 0; f < C_F; ++f) s += pool_f[f] * ldf(Wl, tid * C_F + f, isf);
        float v = tanhf(s);
        if (idx < C_B * C_R) {
            int b = idx / C_R, r = idx % C_R;
            ws_cat[b * 640 + r * C_ID + tid] = v;
        } else if (idx < 2 * C_B * C_R) {
            int j = idx - C_B * C_R;
            int b = j / C_R, r = j % C_R;
            ws_cat[b * 640 + 320 + r * C_ID + tid] = v;
        } else {
            int b = idx - 2 * C_B * C_R;
            stf(d_out, C_B * C_ID + b * C_ID + tid, v, isf);   // tl after src
        }
    }
}

// ---------------------------------------------------------------------------
// K3: src head: h = tanh(cat @ W1^T + b1); src = tanh(h @ W2^T + b2).
// ---------------------------------------------------------------------------
__global__ __launch_bounds__(256) void head_kernel(
    const float* __restrict__ ws_cat,
    const void* __restrict__ W1, const void* __restrict__ b1,
    const void* __restrict__ W2, const void* __restrict__ b2,
    const int* __restrict__ flag, void* __restrict__ d_out)
{
    __shared__ float part[C_ID][8];
    __shared__ float h_s[C_ID];
    int b = blockIdx.x;
    int tid = threadIdx.x;
    int isf = flag[0];
    int o = tid >> 3, seg = tid & 7;
    const float* cat = ws_cat + b * 640;
    float acc = 0.f;
    int j0 = seg * 80;
    for (int j = j0; j < j0 + 80; ++j) acc += cat[j] * ldf(W1, o * 640 + j, isf);
    part[o][seg] = acc;
    __syncthreads();
    if (tid < C_ID) {
        float s = ldf(b1, tid, isf);
        #pragma unroll
        for (int q = 0; q < 8; ++q) s += part[tid][q];
        h_s[tid] = tanhf(s);
    }
    __syncthreads();
    if (tid < C_ID) {
        float s = ldf(b2, tid, isf);
        #pragma unroll
        for (int i = 0; i < C_ID; ++i) s += h_s[i] * ldf(W2, tid * C_ID + i, isf);
        stf(d_out, b * C_ID + tid, tanhf(s), isf);
    }
}

extern "C" void kernel_launch(void* const* d_in, const int* in_sizes, int n_in,
                              void* d_out, int out_size, void* d_ws, size_t ws_size,
                              hipStream_t stream)
{
    const int* user_reviews = (const int*)d_in[0];
    const int* item_reviews = (const int*)d_in[1];
    const int* uids         = (const int*)d_in[2];
    const int* iids         = (const int*)d_in[3];
    const int* user2item    = (const int*)d_in[4];
    const int* item2user    = (const int*)d_in[5];
    const int* rand_reviews = (const int*)d_in[6];
    const void* user_emb = d_in[7];
    const void* item_emb = d_in[8];
    const void* cu_Wc = d_in[9];
    const void* cu_bc = d_in[10];
    const void* cu_Wl = d_in[11];
    const void* cu_bl = d_in[12];
    const void* ci_Wc = d_in[13];
    const void* ci_bc = d_in[14];
    const void* ci_Wl = d_in[15];
    const void* ci_bl = d_in[16];
    const void* t_W1  = d_in[17];
    const void* t_b1  = d_in[18];
    const void* t_W2  = d_in[19];
    const void* t_b2  = d_in[20];
    // d_in[21..23]: fs_* — outputs unused
    const void* te_emb = d_in[24];
    const void* tc_Wc  = d_in[25];
    const void* tc_bc  = d_in[26];
    const void* tc_Wl  = d_in[27];
    const void* tc_bl  = d_in[28];
    // d_in[29..31]: ft_* — unused

    int*   ws_flag = (int*)d_ws;                                   // 256 B reserved
    float* ws_wf   = (float*)((char*)d_ws + 256);                  // 57600 f32
    float* ws_cat  = (float*)((char*)d_ws + 256 + 57600 * 4);      // 128*640 f32

    detect_dtype<<<1, 64, 0, stream>>>((const u32*)user_emb, ws_flag);

    prep_weights<<<225, 256, 0, stream>>>(cu_Wc, ci_Wc, tc_Wc, ws_flag, ws_wf);

    cnn_kernel<<<2 * C_B * C_R + C_B, 256, 0, stream>>>(
        user_reviews, item_reviews, uids, iids, user2item, item2user, rand_reviews,
        user_emb, item_emb, te_emb,
        cu_bc, cu_Wl, cu_bl, ci_bc, ci_Wl, ci_bl, tc_bc, tc_Wl, tc_bl,
        ws_flag, ws_wf, ws_cat, d_out);

    head_kernel<<<C_B, 256, 0, stream>>>(ws_cat, t_W1, t_b1, t_W2, t_b2, ws_flag, d_out);
}

// Round 4
// 246.299 us; speedup vs baseline: 6.8050x; 6.8050x over previous
//
#include <hip/hip_runtime.h>
#include <hip/hip_bf16.h>

// TRANSNET on MI355X — MFMA im2col formulation.
// Per review: GEMM M=256(L) x N=112(F pad) x K=192(3 taps * D64) via
// mfma_f32_16x16x32_bf16, then fused bias+relu+maxpool+linear+tanh.
// Float dtype (bf16 vs f32) detected on device; bf16 confirmed empirically
// (round-3 absmax was exactly 2^-9) but dual path kept for robustness.

#define C_V 50000
#define C_D 64
#define C_F 100
#define C_K 3
#define C_L 256
#define C_R 10
#define C_ID 32
#define C_B 128

typedef unsigned int u32;
typedef unsigned short u16;
typedef __attribute__((ext_vector_type(8))) short bf16x8;
typedef __attribute__((ext_vector_type(4))) float f32x4;

__device__ __forceinline__ float bf2f(u16 h) { union {u32 u; float f;} v; v.u = ((u32)h) << 16; return v.f; }
__device__ __forceinline__ u16 f2bf(float f) {
    union {float f; u32 u;} v; v.f = f;
    u32 u = v.u;
    return (u16)((u + 0x7fffu + ((u >> 16) & 1u)) >> 16);  // RNE
}
__device__ __forceinline__ float ldf(const void* p, int idx, int isf) {
    return isf ? ((const float*)p)[idx] : bf2f(((const u16*)p)[idx]);
}
__device__ __forceinline__ void stf(void* p, int idx, float v, int isf) {
    if (isf) ((float*)p)[idx] = v; else ((u16*)p)[idx] = f2bf(v);
}

// ---------------------------------------------------------------------------
// K-1: dtype probe (0 = bf16, 1 = f32), from user_emb bit patterns.
// ---------------------------------------------------------------------------
__global__ void detect_dtype(const u32* __restrict__ ue, int* __restrict__ flag) {
    int t = threadIdx.x;                 // 64 threads
    u32 w = ue[t];
    u32 e = (w >> 7) & 0xFFu;            // low half-word's bf16 exponent field
    int hit = (e >= 0x70u && e <= 0x7Fu);
    unsigned long long m = __ballot(hit);
    if (t == 0) flag[0] = (__popcll(m) >= 32) ? 0 : 1;
}

// ---------------------------------------------------------------------------
// K0: pre-pack B fragments. B[k][n] = Wc[f=n][kdim=k]; fragment order
// [set][chunk(6)][nt(7)][lane(64)][j(8)] bf16 — exactly the per-lane 16B the
// GEMM loads. f>=100 zero-padded. One thread = one lane-fragment.
// ---------------------------------------------------------------------------
__global__ __launch_bounds__(256) void prep_bfrags(
    const void* __restrict__ cu_Wc, const void* __restrict__ ci_Wc,
    const void* __restrict__ tc_Wc, const int* __restrict__ flag,
    u16* __restrict__ wsB)
{
    int id = blockIdx.x * 256 + threadIdx.x;   // 3*6*7*64 = 8064 total
    if (id >= 3 * 6 * 7 * 64) return;
    int isf  = flag[0];
    int s    = id / 2688;
    int rem  = id % 2688;
    int c    = rem / 448;
    int rem2 = rem % 448;
    int nt   = rem2 / 64;
    int lane = rem2 % 64;
    int f    = nt * 16 + (lane & 15);
    int quad = lane >> 4;
    const void* W = (s == 0) ? cu_Wc : (s == 1) ? ci_Wc : tc_Wc;
    u16 out[8];
    #pragma unroll
    for (int j = 0; j < 8; ++j) {
        int kdim = c * 32 + quad * 8 + j;
        int tap = kdim >> 6, d = kdim & 63;
        float v = (f < C_F) ? ldf(W, (f * C_D + d) * C_K + tap, isf) : 0.f;
        out[j] = f2bf(v);
    }
    *reinterpret_cast<uint4*>(wsB + id * 8) = *reinterpret_cast<const uint4*>(out);
}

// ---------------------------------------------------------------------------
// K2: one block (256 thr = 4 waves) per review (2688 blocks).
// LDS carve (81760 B total, targeting 2 blocks/CU):
//   embS [258][72] bf16 (37152 B) — row p+1 = position p; rows 0/257 zero pad.
//       stride 72 bf16 = 144 B: rows 16B-aligned, ~2-way banks (free).
//   BfS  21504 bf16 (43008 B) — B fragments in lane order.
//   poolS [100][4] f32 (1600 B) — per-wave column maxes.
// ---------------------------------------------------------------------------
__global__ __launch_bounds__(256) void cnn_mfma(
    const int* __restrict__ user_reviews, const int* __restrict__ item_reviews,
    const int* __restrict__ uids, const int* __restrict__ iids,
    const int* __restrict__ user2item, const int* __restrict__ item2user,
    const int* __restrict__ rand_reviews,
    const void* __restrict__ user_emb, const void* __restrict__ item_emb,
    const void* __restrict__ te_emb,
    const void* __restrict__ cu_bc, const void* __restrict__ cu_Wl, const void* __restrict__ cu_bl,
    const void* __restrict__ ci_bc, const void* __restrict__ ci_Wl, const void* __restrict__ ci_bl,
    const void* __restrict__ tc_bc, const void* __restrict__ tc_Wl, const void* __restrict__ tc_bl,
    const int* __restrict__ flag, const u16* __restrict__ wsB,
    float* __restrict__ ws_cat, void* __restrict__ d_out)
{
    __shared__ __align__(16) char smem[81760];
    u16*   embS  = (u16*)smem;                       // 258*72 bf16
    u16*   BfS   = (u16*)(smem + 37152);             // 21504 bf16
    float* poolS = (float*)(smem + 37152 + 43008);   // [100][4]

    const int tid = threadIdx.x;
    const int idx = blockIdx.x;
    const int isf = flag[0];

    const int* toks;
    const void* emb;
    int set;
    const void *bc, *Wl, *bl;

    if (idx < C_B * C_R) {                         // user reviews
        toks = user_reviews + idx * C_L;
        emb = user_emb; set = 0;
        bc = cu_bc; Wl = cu_Wl; bl = cu_bl;
    } else if (idx < 2 * C_B * C_R) {              // item reviews
        int j = idx - C_B * C_R;
        toks = item_reviews + j * C_L;
        emb = item_emb; set = 1;
        bc = ci_bc; Wl = ci_Wl; bl = ci_bl;
    } else {                                       // target review (selected)
        int b = idx - 2 * C_B * C_R;
        const int* t_ = rand_reviews + b * C_L;
        int iid = iids[b];
        int uid = uids[b];
        int fu = -1, fi = -1;
        for (int r = C_R - 1; r >= 0; --r) {       // first match (argmax of bool)
            if (user2item[b * C_R + r] == iid) fu = r;
            if (item2user[b * C_R + r] == uid) fi = r;
        }
        if (fu >= 0)      t_ = user_reviews + (b * C_R + fu) * C_L;
        else if (fi >= 0) t_ = item_reviews + (b * C_R + fi) * C_L;
        toks = t_;
        emb = te_emb; set = 2;
        bc = tc_bc; Wl = tc_Wl; bl = tc_bl;
    }

    // --- stage B fragments (contiguous, coalesced) ---
    {
        const uint4* src = reinterpret_cast<const uint4*>(wsB + set * 21504);
        uint4* dst = reinterpret_cast<uint4*>(BfS);
        for (int i = tid; i < 2688; i += 256) dst[i] = src[i];
    }
    // --- zero pad rows 0 and 257 (36 words each) ---
    if (tid < 36)            ((u32*)embS)[tid] = 0u;
    else if (tid < 72)       ((u32*)embS)[257 * 36 + (tid - 36)] = 0u;

    // --- stage this thread's token embedding row (64 bf16 -> LDS) ---
    {
        int token = toks[tid];
        u16* dst = embS + (tid + 1) * 72;
        if (isf) {
            const float4* srow = reinterpret_cast<const float4*>(
                (const float*)emb + (size_t)token * C_D);
            #pragma unroll
            for (int j = 0; j < 8; ++j) {
                float4 a = srow[2 * j];
                float4 b = srow[2 * j + 1];
                u16 t[8] = {f2bf(a.x), f2bf(a.y), f2bf(a.z), f2bf(a.w),
                            f2bf(b.x), f2bf(b.y), f2bf(b.z), f2bf(b.w)};
                *reinterpret_cast<uint4*>(dst + j * 8) = *reinterpret_cast<const uint4*>(t);
            }
        } else {
            const uint4* srow = reinterpret_cast<const uint4*>(
                (const u16*)emb + (size_t)token * C_D);
            #pragma unroll
            for (int j = 0; j < 8; ++j)
                reinterpret_cast<uint4*>(dst)[j] = srow[j];
        }
    }
    __syncthreads();

    // --- GEMM: wave w handles M rows [w*64, w*64+64), all 7 N tiles ---
    const int lane = tid & 63, wave = tid >> 6;
    const int quad = lane >> 4, mcol = lane & 15;
    const int mbase = wave * 64;

    f32x4 zero4 = {0.f, 0.f, 0.f, 0.f};
    f32x4 acc[4][7];
    #pragma unroll
    for (int mt = 0; mt < 4; ++mt)
        #pragma unroll
        for (int nt = 0; nt < 7; ++nt) acc[mt][nt] = zero4;

    for (int c = 0; c < 6; ++c) {
        const int tap = c >> 1, dh = c & 1;
        bf16x8 bfr[7];
        #pragma unroll
        for (int nt = 0; nt < 7; ++nt)
            bfr[nt] = *reinterpret_cast<const bf16x8*>(BfS + ((c * 7 + nt) * 64 + lane) * 8);
        bf16x8 afr[4];
        #pragma unroll
        for (int mt = 0; mt < 4; ++mt) {
            int row = mbase + mt * 16 + mcol + tap;      // im2col: position m+tap-1 => row m+tap
            afr[mt] = *reinterpret_cast<const bf16x8*>(embS + row * 72 + dh * 32 + quad * 8);
        }
        #pragma unroll
        for (int mt = 0; mt < 4; ++mt)
            #pragma unroll
            for (int nt = 0; nt < 7; ++nt)
                acc[mt][nt] = __builtin_amdgcn_mfma_f32_16x16x32_bf16(
                    afr[mt], bfr[nt], acc[mt][nt], 0, 0, 0);
    }

    // --- maxpool over m (D layout: m = quad*4+reg (+16*mt), f = mcol (+16*nt)) ---
    #pragma unroll
    for (int nt = 0; nt < 7; ++nt) {
        float mv = -1e30f;
        #pragma unroll
        for (int mt = 0; mt < 4; ++mt) {
            mv = fmaxf(mv, fmaxf(fmaxf(acc[mt][nt].x, acc[mt][nt].y),
                                 fmaxf(acc[mt][nt].z, acc[mt][nt].w)));
        }
        mv = fmaxf(mv, __shfl_xor(mv, 16));
        mv = fmaxf(mv, __shfl_xor(mv, 32));
        int f = nt * 16 + mcol;
        if (quad == 0 && f < C_F) poolS[f * 4 + wave] = mv;
    }
    __syncthreads();

    // --- cross-wave max, bias+relu; pooled value parked at poolS[f*4] ---
    if (tid < C_F) {
        float m4 = fmaxf(fmaxf(poolS[tid * 4 + 0], poolS[tid * 4 + 1]),
                         fmaxf(poolS[tid * 4 + 2], poolS[tid * 4 + 3]));
        poolS[tid * 4] = fmaxf(m4 + ldf(bc, tid, isf), 0.f);  // relu(max+b) == max of relu(x+b)
    }
    __syncthreads();

    // --- linear F->ID + tanh, route to ws_cat / tl output ---
    if (tid < C_ID) {
        float s = ldf(bl, tid, isf);
        for (int f = 0; f < C_F; ++f) s += poolS[f * 4] * ldf(Wl, tid * C_F + f, isf);
        float v = tanhf(s);
        if (idx < C_B * C_R) {
            int b = idx / C_R, r = idx % C_R;
            ws_cat[b * 640 + r * C_ID + tid] = v;
        } else if (idx < 2 * C_B * C_R) {
            int j = idx - C_B * C_R;
            int b = j / C_R, r = j % C_R;
            ws_cat[b * 640 + 320 + r * C_ID + tid] = v;
        } else {
            int b = idx - 2 * C_B * C_R;
            stf(d_out, C_B * C_ID + b * C_ID + tid, v, isf);   // tl after src
        }
    }
}

// ---------------------------------------------------------------------------
// K3: src head: h = tanh(cat @ W1^T + b1); src = tanh(h @ W2^T + b2).
// ---------------------------------------------------------------------------
__global__ __launch_bounds__(256) void head_kernel(
    const float* __restrict__ ws_cat,
    const void* __restrict__ W1, const void* __restrict__ b1,
    const void* __restrict__ W2, const void* __restrict__ b2,
    const int* __restrict__ flag, void* __restrict__ d_out)
{
    __shared__ float part[C_ID][8];
    __shared__ float h_s[C_ID];
    int b = blockIdx.x;
    int tid = threadIdx.x;
    int isf = flag[0];
    int o = tid >> 3, seg = tid & 7;
    const float* cat = ws_cat + b * 640;
    float acc = 0.f;
    int j0 = seg * 80;
    for (int j = j0; j < j0 + 80; ++j) acc += cat[j] * ldf(W1, o * 640 + j, isf);
    part[o][seg] = acc;
    __syncthreads();
    if (tid < C_ID) {
        float s = ldf(b1, tid, isf);
        #pragma unroll
        for (int q = 0; q < 8; ++q) s += part[tid][q];
        h_s[tid] = tanhf(s);
    }
    __syncthreads();
    if (tid < C_ID) {
        float s = ldf(b2, tid, isf);
        #pragma unroll
        for (int i = 0; i < C_ID; ++i) s += h_s[i] * ldf(W2, tid * C_ID + i, isf);
        stf(d_out, b * C_ID + tid, tanhf(s), isf);
    }
}

extern "C" void kernel_launch(void* const* d_in, const int* in_sizes, int n_in,
                              void* d_out, int out_size, void* d_ws, size_t ws_size,
                              hipStream_t stream)
{
    const int* user_reviews = (const int*)d_in[0];
    const int* item_reviews = (const int*)d_in[1];
    const int* uids         = (const int*)d_in[2];
    const int* iids         = (const int*)d_in[3];
    const int* user2item    = (const int*)d_in[4];
    const int* item2user    = (const int*)d_in[5];
    const int* rand_reviews = (const int*)d_in[6];
    const void* user_emb = d_in[7];
    const void* item_emb = d_in[8];
    const void* cu_Wc = d_in[9];
    const void* cu_bc = d_in[10];
    const void* cu_Wl = d_in[11];
    const void* cu_bl = d_in[12];
    const void* ci_Wc = d_in[13];
    const void* ci_bc = d_in[14];
    const void* ci_Wl = d_in[15];
    const void* ci_bl = d_in[16];
    const void* t_W1  = d_in[17];
    const void* t_b1  = d_in[18];
    const void* t_W2  = d_in[19];
    const void* t_b2  = d_in[20];
    // d_in[21..23]: fs_* — outputs unused
    const void* te_emb = d_in[24];
    const void* tc_Wc  = d_in[25];
    const void* tc_bc  = d_in[26];
    const void* tc_Wl  = d_in[27];
    const void* tc_bl  = d_in[28];
    // d_in[29..31]: ft_* — unused

    int*   ws_flag = (int*)d_ws;                                    // 256 B
    u16*   ws_B    = (u16*)((char*)d_ws + 256);                     // 129024 B
    float* ws_cat  = (float*)((char*)d_ws + 256 + 129024);          // 128*640 f32

    detect_dtype<<<1, 64, 0, stream>>>((const u32*)user_emb, ws_flag);

    prep_bfrags<<<32, 256, 0, stream>>>(cu_Wc, ci_Wc, tc_Wc, ws_flag, ws_B);

    cnn_mfma<<<2 * C_B * C_R + C_B, 256, 0, stream>>>(
        user_reviews, item_reviews, uids, iids, user2item, item2user, rand_reviews,
        user_emb, item_emb, te_emb,
        cu_bc, cu_Wl, cu_bl, ci_bc, ci_Wl, ci_bl, tc_bc, tc_Wl, tc_bl,
        ws_flag, ws_B, ws_cat, d_out);

    head_kernel<<<C_B, 256, 0, stream>>>(ws_cat, t_W1, t_b1, t_W2, t_b2, ws_flag, d_out);
}

// Round 5
// 210.728 us; speedup vs baseline: 7.9537x; 1.1688x over previous
//
#include <hip/hip_runtime.h>
#include <hip/hip_bf16.h>

// TRANSNET on MI355X — MFMA im2col, occupancy-optimized.
// Per review: GEMM M=256(L) x N=112(Fpad) x K=192(3 taps * D64) via
// mfma_f32_16x16x32_bf16 in TWO N-passes (acc 64 VGPR), B-fragments read
// directly from a pre-packed global buffer (L2-resident), LDS = emb only
// (38.8 KB -> 4 blocks/CU by LDS; launch_bounds(256,3) -> >=3 blocks/CU).
// dtype flag (bf16 vs f32) derived per-wave in every kernel (no extra launch).

#define C_V 50000
#define C_D 64
#define C_F 100
#define C_K 3
#define C_L 256
#define C_R 10
#define C_ID 32
#define C_B 128

typedef unsigned int u32;
typedef unsigned short u16;
typedef __attribute__((ext_vector_type(8))) short bf16x8;
typedef __attribute__((ext_vector_type(4))) float f32x4;

__device__ __forceinline__ float bf2f(u16 h) { union {u32 u; float f;} v; v.u = ((u32)h) << 16; return v.f; }
__device__ __forceinline__ u16 f2bf(float f) {
    union {float f; u32 u;} v; v.f = f;
    u32 u = v.u;
    return (u16)((u + 0x7fffu + ((u >> 16) & 1u)) >> 16);  // RNE
}
__device__ __forceinline__ float ldf(const void* p, int idx, int isf) {
    return isf ? ((const float*)p)[idx] : bf2f(((const u16*)p)[idx]);
}
__device__ __forceinline__ void stf(void* p, int idx, float v, int isf) {
    if (isf) ((float*)p)[idx] = v; else ((u16*)p)[idx] = f2bf(v);
}
// Per-wave dtype probe: bf16 halves of N(0,0.1) values have exponent field in
// [0x70,0x7F]; f32 low-16 mantissa bits hit that window ~1/16 of the time.
__device__ __forceinline__ int detect_isf(const u32* __restrict__ ue, int lane) {
    u32 w = ue[lane];
    u32 e = (w >> 7) & 0xFFu;
    int hit = (e >= 0x70u && e <= 0x7Fu);
    unsigned long long m = __ballot(hit);
    return (__popcll(m) >= 32) ? 0 : 1;
}

// ---------------------------------------------------------------------------
// K0: pre-pack B fragments: [set(3)][c(6)][nt(7)][lane(64)][j(8)] bf16 —
// exactly the per-lane 16B the GEMM loads. f>=100 zero-padded.
// ---------------------------------------------------------------------------
__global__ __launch_bounds__(256) void prep_bfrags(
    const void* __restrict__ cu_Wc, const void* __restrict__ ci_Wc,
    const void* __restrict__ tc_Wc, const u32* __restrict__ ue,
    u16* __restrict__ wsB)
{
    int tid = threadIdx.x;
    int isf = detect_isf(ue, tid & 63);
    int id = blockIdx.x * 256 + tid;           // 3*6*7*64 = 8064 total
    if (id >= 3 * 6 * 7 * 64) return;
    int s    = id / 2688;
    int rem  = id % 2688;
    int c    = rem / 448;
    int rem2 = rem % 448;
    int nt   = rem2 / 64;
    int lane = rem2 % 64;
    int f    = nt * 16 + (lane & 15);
    int quad = lane >> 4;
    const void* W = (s == 0) ? cu_Wc : (s == 1) ? ci_Wc : tc_Wc;
    u16 out[8];
    #pragma unroll
    for (int j = 0; j < 8; ++j) {
        int kdim = c * 32 + quad * 8 + j;
        int tap = kdim >> 6, d = kdim & 63;
        float v = (f < C_F) ? ldf(W, (f * C_D + d) * C_K + tap, isf) : 0.f;
        out[j] = f2bf(v);
    }
    *reinterpret_cast<uint4*>(wsB + id * 8) = *reinterpret_cast<const uint4*>(out);
}

// ---------------------------------------------------------------------------
// K1: one block (4 waves) per review (2688). LDS: embS [258][72] bf16
// (37152 B, rows 16B-aligned) + poolS [100][4] f32 (1600 B) ~= 38.8 KB.
// ---------------------------------------------------------------------------
__global__ __launch_bounds__(256, 3) void cnn_mfma(
    const int* __restrict__ user_reviews, const int* __restrict__ item_reviews,
    const int* __restrict__ uids, const int* __restrict__ iids,
    const int* __restrict__ user2item, const int* __restrict__ item2user,
    const int* __restrict__ rand_reviews,
    const void* __restrict__ user_emb, const void* __restrict__ item_emb,
    const void* __restrict__ te_emb,
    const void* __restrict__ cu_bc, const void* __restrict__ cu_Wl, const void* __restrict__ cu_bl,
    const void* __restrict__ ci_bc, const void* __restrict__ ci_Wl, const void* __restrict__ ci_bl,
    const void* __restrict__ tc_bc, const void* __restrict__ tc_Wl, const void* __restrict__ tc_bl,
    const u16* __restrict__ wsB,
    float* __restrict__ ws_cat, void* __restrict__ d_out)
{
    __shared__ __align__(16) char smem[37152 + 1600];
    u16*   embS  = (u16*)smem;                 // 258*72 bf16; row p+1 = pos p
    float* poolS = (float*)(smem + 37152);     // [100][4]
    float* partS = (float*)smem;               // reused for linear partials (after GEMM)

    const int tid = threadIdx.x;
    const int idx = blockIdx.x;
    const int lane = tid & 63, wave = tid >> 6;
    const int isf = detect_isf((const u32*)user_emb, lane);

    const int* toks;
    const void* emb;
    int set;
    const void *bc, *Wl, *bl;

    if (idx < C_B * C_R) {                         // user reviews
        toks = user_reviews + idx * C_L;
        emb = user_emb; set = 0;
        bc = cu_bc; Wl = cu_Wl; bl = cu_bl;
    } else if (idx < 2 * C_B * C_R) {              // item reviews
        int j = idx - C_B * C_R;
        toks = item_reviews + j * C_L;
        emb = item_emb; set = 1;
        bc = ci_bc; Wl = ci_Wl; bl = ci_bl;
    } else {                                       // target review (selected)
        int b = idx - 2 * C_B * C_R;
        const int* t_ = rand_reviews + b * C_L;
        int iid = iids[b];
        int uid = uids[b];
        int fu = -1, fi = -1;
        for (int r = C_R - 1; r >= 0; --r) {       // first match (argmax of bool)
            if (user2item[b * C_R + r] == iid) fu = r;
            if (item2user[b * C_R + r] == uid) fi = r;
        }
        if (fu >= 0)      t_ = user_reviews + (b * C_R + fu) * C_L;
        else if (fi >= 0) t_ = item_reviews + (b * C_R + fi) * C_L;
        toks = t_;
        emb = te_emb; set = 2;
        bc = tc_bc; Wl = tc_Wl; bl = tc_bl;
    }

    // zero pad rows 0 and 257 (36 u32 words each)
    if (tid < 36)            ((u32*)embS)[tid] = 0u;
    else if (tid < 72)       ((u32*)embS)[257 * 36 + (tid - 36)] = 0u;

    // stage this thread's token embedding row (64 bf16 -> LDS)
    {
        int token = toks[tid];
        u16* dst = embS + (tid + 1) * 72;
        if (isf) {
            const float4* srow = reinterpret_cast<const float4*>(
                (const float*)emb + (size_t)token * C_D);
            #pragma unroll
            for (int j = 0; j < 8; ++j) {
                float4 a = srow[2 * j];
                float4 b = srow[2 * j + 1];
                u16 t[8] = {f2bf(a.x), f2bf(a.y), f2bf(a.z), f2bf(a.w),
                            f2bf(b.x), f2bf(b.y), f2bf(b.z), f2bf(b.w)};
                *reinterpret_cast<uint4*>(dst + j * 8) = *reinterpret_cast<const uint4*>(t);
            }
        } else {
            const uint4* srow = reinterpret_cast<const uint4*>(
                (const u16*)emb + (size_t)token * C_D);
            #pragma unroll
            for (int j = 0; j < 8; ++j)
                reinterpret_cast<uint4*>(dst)[j] = srow[j];
        }
    }
    __syncthreads();

    const int quad = lane >> 4, mcol = lane & 15;
    const int mbase = wave * 64;
    const u16* BfG = wsB + set * 21504;   // this set's fragments

    // ---- pass 0: nt 0..3 (f 0..63) ----
    {
        f32x4 acc[4][4];
        #pragma unroll
        for (int mt = 0; mt < 4; ++mt)
            #pragma unroll
            for (int nt = 0; nt < 4; ++nt) acc[mt][nt] = (f32x4){0.f,0.f,0.f,0.f};
        #pragma unroll
        for (int c = 0; c < 6; ++c) {
            const int tap = c >> 1, dh = c & 1;
            bf16x8 bfr[4];
            #pragma unroll
            for (int nt = 0; nt < 4; ++nt)
                bfr[nt] = *reinterpret_cast<const bf16x8*>(BfG + ((c * 7 + nt) * 64 + lane) * 8);
            bf16x8 afr[4];
            #pragma unroll
            for (int mt = 0; mt < 4; ++mt) {
                int row = mbase + mt * 16 + mcol + tap;
                afr[mt] = *reinterpret_cast<const bf16x8*>(embS + row * 72 + dh * 32 + quad * 8);
            }
            #pragma unroll
            for (int mt = 0; mt < 4; ++mt)
                #pragma unroll
                for (int nt = 0; nt < 4; ++nt)
                    acc[mt][nt] = __builtin_amdgcn_mfma_f32_16x16x32_bf16(
                        afr[mt], bfr[nt], acc[mt][nt], 0, 0, 0);
        }
        #pragma unroll
        for (int nt = 0; nt < 4; ++nt) {
            float mv = -1e30f;
            #pragma unroll
            for (int mt = 0; mt < 4; ++mt)
                mv = fmaxf(mv, fmaxf(fmaxf(acc[mt][nt].x, acc[mt][nt].y),
                                     fmaxf(acc[mt][nt].z, acc[mt][nt].w)));
            mv = fmaxf(mv, __shfl_xor(mv, 16));
            mv = fmaxf(mv, __shfl_xor(mv, 32));
            if (quad == 0) poolS[(nt * 16 + mcol) * 4 + wave] = mv;   // f<=63<100
        }
    }
    // ---- pass 1: nt 4..6 (f 64..111, pad-zeros beyond 99) ----
    {
        f32x4 acc[4][3];
        #pragma unroll
        for (int mt = 0; mt < 4; ++mt)
            #pragma unroll
            for (int nt = 0; nt < 3; ++nt) acc[mt][nt] = (f32x4){0.f,0.f,0.f,0.f};
        #pragma unroll
        for (int c = 0; c < 6; ++c) {
            const int tap = c >> 1, dh = c & 1;
            bf16x8 bfr[3];
            #pragma unroll
            for (int nt = 0; nt < 3; ++nt)
                bfr[nt] = *reinterpret_cast<const bf16x8*>(BfG + ((c * 7 + 4 + nt) * 64 + lane) * 8);
            bf16x8 afr[4];
            #pragma unroll
            for (int mt = 0; mt < 4; ++mt) {
                int row = mbase + mt * 16 + mcol + tap;
                afr[mt] = *reinterpret_cast<const bf16x8*>(embS + row * 72 + dh * 32 + quad * 8);
            }
            #pragma unroll
            for (int mt = 0; mt < 4; ++mt)
                #pragma unroll
                for (int nt = 0; nt < 3; ++nt)
                    acc[mt][nt] = __builtin_amdgcn_mfma_f32_16x16x32_bf16(
                        afr[mt], bfr[nt], acc[mt][nt], 0, 0, 0);
        }
        #pragma unroll
        for (int nt = 0; nt < 3; ++nt) {
            float mv = -1e30f;
            #pragma unroll
            for (int mt = 0; mt < 4; ++mt)
                mv = fmaxf(mv, fmaxf(fmaxf(acc[mt][nt].x, acc[mt][nt].y),
                                     fmaxf(acc[mt][nt].z, acc[mt][nt].w)));
            mv = fmaxf(mv, __shfl_xor(mv, 16));
            mv = fmaxf(mv, __shfl_xor(mv, 32));
            int f = (4 + nt) * 16 + mcol;
            if (quad == 0 && f < C_F) poolS[f * 4 + wave] = mv;
        }
    }
    __syncthreads();

    // cross-wave max + bias + relu -> poolS[f*4]
    if (tid < C_F) {
        float m4 = fmaxf(fmaxf(poolS[tid * 4 + 0], poolS[tid * 4 + 1]),
                         fmaxf(poolS[tid * 4 + 2], poolS[tid * 4 + 3]));
        poolS[tid * 4] = fmaxf(m4 + ldf(bc, tid, isf), 0.f);
    }
    __syncthreads();

    // wide linear F->ID: 8 threads per output, 12-13 f each
    {
        int o = tid >> 3, seg = tid & 7;
        int f0 = (seg < 4) ? seg * 13 : 52 + (seg - 4) * 12;
        int cnt = (seg < 4) ? 13 : 12;
        float acc = 0.f;
        for (int q = 0; q < cnt; ++q) {
            int f = f0 + q;
            acc += poolS[f * 4] * ldf(Wl, o * C_F + f, isf);
        }
        partS[o * 8 + seg] = acc;
    }
    __syncthreads();
    if (tid < C_ID) {
        float s = ldf(bl, tid, isf);
        #pragma unroll
        for (int q = 0; q < 8; ++q) s += partS[tid * 8 + q];
        float v = tanhf(s);
        if (idx < C_B * C_R) {
            int b = idx / C_R, r = idx % C_R;
            ws_cat[b * 640 + r * C_ID + tid] = v;
        } else if (idx < 2 * C_B * C_R) {
            int j = idx - C_B * C_R;
            int b = j / C_R, r = j % C_R;
            ws_cat[b * 640 + 320 + r * C_ID + tid] = v;
        } else {
            int b = idx - 2 * C_B * C_R;
            stf(d_out, C_B * C_ID + b * C_ID + tid, v, isf);   // tl after src
        }
    }
}

// ---------------------------------------------------------------------------
// K2: src head: h = tanh(cat @ W1^T + b1); src = tanh(h @ W2^T + b2).
// ---------------------------------------------------------------------------
__global__ __launch_bounds__(256) void head_kernel(
    const float* __restrict__ ws_cat,
    const void* __restrict__ W1, const void* __restrict__ b1,
    const void* __restrict__ W2, const void* __restrict__ b2,
    const u32* __restrict__ ue, void* __restrict__ d_out)
{
    __shared__ float part[C_ID][8];
    __shared__ float h_s[C_ID];
    int b = blockIdx.x;
    int tid = threadIdx.x;
    int isf = detect_isf(ue, tid & 63);
    int o = tid >> 3, seg = tid & 7;
    const float* cat = ws_cat + b * 640;
    float acc = 0.f;
    int j0 = seg * 80;
    for (int j = j0; j < j0 + 80; ++j) acc += cat[j] * ldf(W1, o * 640 + j, isf);
    part[o][seg] = acc;
    __syncthreads();
    if (tid < C_ID) {
        float s = ldf(b1, tid, isf);
        #pragma unroll
        for (int q = 0; q < 8; ++q) s += part[tid][q];
        h_s[tid] = tanhf(s);
    }
    __syncthreads();
    if (tid < C_ID) {
        float s = ldf(b2, tid, isf);
        #pragma unroll
        for (int i = 0; i < C_ID; ++i) s += h_s[i] * ldf(W2, tid * C_ID + i, isf);
        stf(d_out, b * C_ID + tid, tanhf(s), isf);
    }
}

extern "C" void kernel_launch(void* const* d_in, const int* in_sizes, int n_in,
                              void* d_out, int out_size, void* d_ws, size_t ws_size,
                              hipStream_t stream)
{
    const int* user_reviews = (const int*)d_in[0];
    const int* item_reviews = (const int*)d_in[1];
    const int* uids         = (const int*)d_in[2];
    const int* iids         = (const int*)d_in[3];
    const int* user2item    = (const int*)d_in[4];
    const int* item2user    = (const int*)d_in[5];
    const int* rand_reviews = (const int*)d_in[6];
    const void* user_emb = d_in[7];
    const void* item_emb = d_in[8];
    const void* cu_Wc = d_in[9];
    const void* cu_bc = d_in[10];
    const void* cu_Wl = d_in[11];
    const void* cu_bl = d_in[12];
    const void* ci_Wc = d_in[13];
    const void* ci_bc = d_in[14];
    const void* ci_Wl = d_in[15];
    const void* ci_bl = d_in[16];
    const void* t_W1  = d_in[17];
    const void* t_b1  = d_in[18];
    const void* t_W2  = d_in[19];
    const void* t_b2  = d_in[20];
    // d_in[21..23]: fs_* — outputs unused
    const void* te_emb = d_in[24];
    const void* tc_Wc  = d_in[25];
    const void* tc_bc  = d_in[26];
    const void* tc_Wl  = d_in[27];
    const void* tc_bl  = d_in[28];
    // d_in[29..31]: ft_* — unused

    u16*   ws_B   = (u16*)d_ws;                                 // 129024 B
    float* ws_cat = (float*)((char*)d_ws + 129536);             // 128*640 f32

    prep_bfrags<<<32, 256, 0, stream>>>(cu_Wc, ci_Wc, tc_Wc,
                                        (const u32*)user_emb, ws_B);

    cnn_mfma<<<2 * C_B * C_R + C_B, 256, 0, stream>>>(
        user_reviews, item_reviews, uids, iids, user2item, item2user, rand_reviews,
        user_emb, item_emb, te_emb,
        cu_bc, cu_Wl, cu_bl, ci_bc, ci_Wl, ci_bl, tc_bc, tc_Wl, tc_bl,
        ws_B, ws_cat, d_out);

    head_kernel<<<C_B, 256, 0, stream>>>(ws_cat, t_W1, t_b1, t_W2, t_b2,
                                         (const u32*)user_emb, d_out);
}

// Round 6
// 207.955 us; speedup vs baseline: 8.0598x; 1.0133x over previous
//
#include <hip/hip_runtime.h>
#include <hip/hip_bf16.h>

// TRANSNET on MI355X — MFMA im2col, round 6: occupancy (4 blocks/CU) +
// XCD-aware review remap for embedding-table L2 locality.
// Per review: GEMM M=256(L) x N=112(Fpad) x K=192 via mfma_f32_16x16x32_bf16
// in two N-passes; B-fragments pre-packed in global (L2-hot); LDS = emb only.

#define C_V 50000
#define C_D 64
#define C_F 100
#define C_K 3
#define C_L 256
#define C_R 10
#define C_ID 32
#define C_B 128

typedef unsigned int u32;
typedef unsigned short u16;
typedef __attribute__((ext_vector_type(8))) short bf16x8;
typedef __attribute__((ext_vector_type(4))) float f32x4;

__device__ __forceinline__ float bf2f(u16 h) { union {u32 u; float f;} v; v.u = ((u32)h) << 16; return v.f; }
__device__ __forceinline__ u16 f2bf(float f) {
    union {float f; u32 u;} v; v.f = f;
    u32 u = v.u;
    return (u16)((u + 0x7fffu + ((u >> 16) & 1u)) >> 16);  // RNE
}
__device__ __forceinline__ float ldf(const void* p, int idx, int isf) {
    return isf ? ((const float*)p)[idx] : bf2f(((const u16*)p)[idx]);
}
__device__ __forceinline__ void stf(void* p, int idx, float v, int isf) {
    if (isf) ((float*)p)[idx] = v; else ((u16*)p)[idx] = f2bf(v);
}
// Per-wave dtype probe: bf16 halves of N(0,0.1) values have exponent field in
// [0x70,0x7F]; f32 low-16 mantissa bits hit that window ~1/16 of the time.
__device__ __forceinline__ int detect_isf(const u32* __restrict__ ue, int lane) {
    u32 w = ue[lane];
    u32 e = (w >> 7) & 0xFFu;
    int hit = (e >= 0x70u && e <= 0x7Fu);
    unsigned long long m = __ballot(hit);
    return (__popcll(m) >= 32) ? 0 : 1;
}

// ---------------------------------------------------------------------------
// K0: pre-pack B fragments: [set(3)][c(6)][nt(7)][lane(64)][j(8)] bf16 —
// exactly the per-lane 16B the GEMM loads. f>=100 zero-padded.
// ---------------------------------------------------------------------------
__global__ __launch_bounds__(256) void prep_bfrags(
    const void* __restrict__ cu_Wc, const void* __restrict__ ci_Wc,
    const void* __restrict__ tc_Wc, const u32* __restrict__ ue,
    u16* __restrict__ wsB)
{
    int tid = threadIdx.x;
    int isf = detect_isf(ue, tid & 63);
    int id = blockIdx.x * 256 + tid;           // 3*6*7*64 = 8064 total
    if (id >= 3 * 6 * 7 * 64) return;
    int s    = id / 2688;
    int rem  = id % 2688;
    int c    = rem / 448;
    int rem2 = rem % 448;
    int nt   = rem2 / 64;
    int lane = rem2 % 64;
    int f    = nt * 16 + (lane & 15);
    int quad = lane >> 4;
    const void* W = (s == 0) ? cu_Wc : (s == 1) ? ci_Wc : tc_Wc;
    u16 out[8];
    #pragma unroll
    for (int j = 0; j < 8; ++j) {
        int kdim = c * 32 + quad * 8 + j;
        int tap = kdim >> 6, d = kdim & 63;
        float v = (f < C_F) ? ldf(W, (f * C_D + d) * C_K + tap, isf) : 0.f;
        out[j] = f2bf(v);
    }
    *reinterpret_cast<uint4*>(wsB + id * 8) = *reinterpret_cast<const uint4*>(out);
}

// ---------------------------------------------------------------------------
// K1: one block (4 waves) per review (2688). LDS ~38.8 KB -> 4 blocks/CU.
// Review index XCD-remapped: round-robin dispatch => contiguous review range
// per XCD => each XCD's L2 mostly serves ONE embedding table.
// ---------------------------------------------------------------------------
__global__ __launch_bounds__(256, 4) void cnn_mfma(
    const int* __restrict__ user_reviews, const int* __restrict__ item_reviews,
    const int* __restrict__ uids, const int* __restrict__ iids,
    const int* __restrict__ user2item, const int* __restrict__ item2user,
    const int* __restrict__ rand_reviews,
    const void* __restrict__ user_emb, const void* __restrict__ item_emb,
    const void* __restrict__ te_emb,
    const void* __restrict__ cu_bc, const void* __restrict__ cu_Wl, const void* __restrict__ cu_bl,
    const void* __restrict__ ci_bc, const void* __restrict__ ci_Wl, const void* __restrict__ ci_bl,
    const void* __restrict__ tc_bc, const void* __restrict__ tc_Wl, const void* __restrict__ tc_bl,
    const u16* __restrict__ wsB,
    float* __restrict__ ws_cat, void* __restrict__ d_out)
{
    __shared__ __align__(16) char smem[37152 + 1600];
    u16*   embS  = (u16*)smem;                 // 258*72 bf16; row p+1 = pos p
    float* poolS = (float*)(smem + 37152);     // [100][4]
    float* partS = (float*)smem;               // reused for linear partials (after GEMM)

    const int tid = threadIdx.x;
    // XCD-aware remap: blocks go to XCD (blockIdx%8); give each XCD a
    // contiguous review range so its L2 holds mostly one table. 2688 = 8*336.
    const int idx = (blockIdx.x & 7) * 336 + (blockIdx.x >> 3);
    const int lane = tid & 63, wave = tid >> 6;
    const int isf = detect_isf((const u32*)user_emb, lane);

    const int* toks;
    const void* emb;
    int set;
    const void *bc, *Wl, *bl;

    if (idx < C_B * C_R) {                         // user reviews
        toks = user_reviews + idx * C_L;
        emb = user_emb; set = 0;
        bc = cu_bc; Wl = cu_Wl; bl = cu_bl;
    } else if (idx < 2 * C_B * C_R) {              // item reviews
        int j = idx - C_B * C_R;
        toks = item_reviews + j * C_L;
        emb = item_emb; set = 1;
        bc = ci_bc; Wl = ci_Wl; bl = ci_bl;
    } else {                                       // target review (selected)
        int b = idx - 2 * C_B * C_R;
        const int* t_ = rand_reviews + b * C_L;
        int iid = iids[b];
        int uid = uids[b];
        int fu = -1, fi = -1;
        for (int r = C_R - 1; r >= 0; --r) {       // first match (argmax of bool)
            if (user2item[b * C_R + r] == iid) fu = r;
            if (item2user[b * C_R + r] == uid) fi = r;
        }
        if (fu >= 0)      t_ = user_reviews + (b * C_R + fu) * C_L;
        else if (fi >= 0) t_ = item_reviews + (b * C_R + fi) * C_L;
        toks = t_;
        emb = te_emb; set = 2;
        bc = tc_bc; Wl = tc_Wl; bl = tc_bl;
    }

    // zero pad rows 0 and 257 (36 u32 words each)
    if (tid < 36)            ((u32*)embS)[tid] = 0u;
    else if (tid < 72)       ((u32*)embS)[257 * 36 + (tid - 36)] = 0u;

    // stage this thread's token embedding row (64 bf16 -> LDS)
    {
        int token = toks[tid];
        u16* dst = embS + (tid + 1) * 72;
        if (isf) {
            const float4* srow = reinterpret_cast<const float4*>(
                (const float*)emb + (size_t)token * C_D);
            #pragma unroll
            for (int j = 0; j < 8; ++j) {
                float4 a = srow[2 * j];
                float4 b = srow[2 * j + 1];
                u16 t[8] = {f2bf(a.x), f2bf(a.y), f2bf(a.z), f2bf(a.w),
                            f2bf(b.x), f2bf(b.y), f2bf(b.z), f2bf(b.w)};
                *reinterpret_cast<uint4*>(dst + j * 8) = *reinterpret_cast<const uint4*>(t);
            }
        } else {
            const uint4* srow = reinterpret_cast<const uint4*>(
                (const u16*)emb + (size_t)token * C_D);
            #pragma unroll
            for (int j = 0; j < 8; ++j)
                reinterpret_cast<uint4*>(dst)[j] = srow[j];
        }
    }
    __syncthreads();

    const int quad = lane >> 4, mcol = lane & 15;
    const int mbase = wave * 64;
    const u16* BfG = wsB + set * 21504;   // this set's fragments

    // ---- pass 0: nt 0..3 (f 0..63) ----
    {
        f32x4 acc[4][4];
        #pragma unroll
        for (int mt = 0; mt < 4; ++mt)
            #pragma unroll
            for (int nt = 0; nt < 4; ++nt) acc[mt][nt] = (f32x4){0.f,0.f,0.f,0.f};
        #pragma unroll
        for (int c = 0; c < 6; ++c) {
            const int tap = c >> 1, dh = c & 1;
            bf16x8 bfr[4];
            #pragma unroll
            for (int nt = 0; nt < 4; ++nt)
                bfr[nt] = *reinterpret_cast<const bf16x8*>(BfG + ((c * 7 + nt) * 64 + lane) * 8);
            bf16x8 afr[4];
            #pragma unroll
            for (int mt = 0; mt < 4; ++mt) {
                int row = mbase + mt * 16 + mcol + tap;
                afr[mt] = *reinterpret_cast<const bf16x8*>(embS + row * 72 + dh * 32 + quad * 8);
            }
            #pragma unroll
            for (int mt = 0; mt < 4; ++mt)
                #pragma unroll
                for (int nt = 0; nt < 4; ++nt)
                    acc[mt][nt] = __builtin_amdgcn_mfma_f32_16x16x32_bf16(
                        afr[mt], bfr[nt], acc[mt][nt], 0, 0, 0);
        }
        #pragma unroll
        for (int nt = 0; nt < 4; ++nt) {
            float mv = -1e30f;
            #pragma unroll
            for (int mt = 0; mt < 4; ++mt)
                mv = fmaxf(mv, fmaxf(fmaxf(acc[mt][nt].x, acc[mt][nt].y),
                                     fmaxf(acc[mt][nt].z, acc[mt][nt].w)));
            mv = fmaxf(mv, __shfl_xor(mv, 16));
            mv = fmaxf(mv, __shfl_xor(mv, 32));
            if (quad == 0) poolS[(nt * 16 + mcol) * 4 + wave] = mv;   // f<=63<100
        }
    }
    // ---- pass 1: nt 4..6 (f 64..111, pad-zeros beyond 99) ----
    {
        f32x4 acc[4][3];
        #pragma unroll
        for (int mt = 0; mt < 4; ++mt)
            #pragma unroll
            for (int nt = 0; nt < 3; ++nt) acc[mt][nt] = (f32x4){0.f,0.f,0.f,0.f};
        #pragma unroll
        for (int c = 0; c < 6; ++c) {
            const int tap = c >> 1, dh = c & 1;
            bf16x8 bfr[3];
            #pragma unroll
            for (int nt = 0; nt < 3; ++nt)
                bfr[nt] = *reinterpret_cast<const bf16x8*>(BfG + ((c * 7 + 4 + nt) * 64 + lane) * 8);
            bf16x8 afr[4];
            #pragma unroll
            for (int mt = 0; mt < 4; ++mt) {
                int row = mbase + mt * 16 + mcol + tap;
                afr[mt] = *reinterpret_cast<const bf16x8*>(embS + row * 72 + dh * 32 + quad * 8);
            }
            #pragma unroll
            for (int mt = 0; mt < 4; ++mt)
                #pragma unroll
                for (int nt = 0; nt < 3; ++nt)
                    acc[mt][nt] = __builtin_amdgcn_mfma_f32_16x16x32_bf16(
                        afr[mt], bfr[nt], acc[mt][nt], 0, 0, 0);
        }
        #pragma unroll
        for (int nt = 0; nt < 3; ++nt) {
            float mv = -1e30f;
            #pragma unroll
            for (int mt = 0; mt < 4; ++mt)
                mv = fmaxf(mv, fmaxf(fmaxf(acc[mt][nt].x, acc[mt][nt].y),
                                     fmaxf(acc[mt][nt].z, acc[mt][nt].w)));
            mv = fmaxf(mv, __shfl_xor(mv, 16));
            mv = fmaxf(mv, __shfl_xor(mv, 32));
            int f = (4 + nt) * 16 + mcol;
            if (quad == 0 && f < C_F) poolS[f * 4 + wave] = mv;
        }
    }
    __syncthreads();

    // cross-wave max + bias + relu -> poolS[f*4]
    if (tid < C_F) {
        float m4 = fmaxf(fmaxf(poolS[tid * 4 + 0], poolS[tid * 4 + 1]),
                         fmaxf(poolS[tid * 4 + 2], poolS[tid * 4 + 3]));
        poolS[tid * 4] = fmaxf(m4 + ldf(bc, tid, isf), 0.f);
    }
    __syncthreads();

    // wide linear F->ID: 8 threads per output, 12-13 f each
    {
        int o = tid >> 3, seg = tid & 7;
        int f0 = (seg < 4) ? seg * 13 : 52 + (seg - 4) * 12;
        int cnt = (seg < 4) ? 13 : 12;
        float acc = 0.f;
        for (int q = 0; q < cnt; ++q) {
            int f = f0 + q;
            acc += poolS[f * 4] * ldf(Wl, o * C_F + f, isf);
        }
        partS[o * 8 + seg] = acc;
    }
    __syncthreads();
    if (tid < C_ID) {
        float s = ldf(bl, tid, isf);
        #pragma unroll
        for (int q = 0; q < 8; ++q) s += partS[tid * 8 + q];
        float v = tanhf(s);
        if (idx < C_B * C_R) {
            int b = idx / C_R, r = idx % C_R;
            ws_cat[b * 640 + r * C_ID + tid] = v;
        } else if (idx < 2 * C_B * C_R) {
            int j = idx - C_B * C_R;
            int b = j / C_R, r = j % C_R;
            ws_cat[b * 640 + 320 + r * C_ID + tid] = v;
        } else {
            int b = idx - 2 * C_B * C_R;
            stf(d_out, C_B * C_ID + b * C_ID + tid, v, isf);   // tl after src
        }
    }
}

// ---------------------------------------------------------------------------
// K2: src head: h = tanh(cat @ W1^T + b1); src = tanh(h @ W2^T + b2).
// ---------------------------------------------------------------------------
__global__ __launch_bounds__(256) void head_kernel(
    const float* __restrict__ ws_cat,
    const void* __restrict__ W1, const void* __restrict__ b1,
    const void* __restrict__ W2, const void* __restrict__ b2,
    const u32* __restrict__ ue, void* __restrict__ d_out)
{
    __shared__ float part[C_ID][8];
    __shared__ float h_s[C_ID];
    int b = blockIdx.x;
    int tid = threadIdx.x;
    int isf = detect_isf(ue, tid & 63);
    int o = tid >> 3, seg = tid & 7;
    const float* cat = ws_cat + b * 640;
    float acc = 0.f;
    int j0 = seg * 80;
    for (int j = j0; j < j0 + 80; ++j) acc += cat[j] * ldf(W1, o * 640 + j, isf);
    part[o][seg] = acc;
    __syncthreads();
    if (tid < C_ID) {
        float s = ldf(b1, tid, isf);
        #pragma unroll
        for (int q = 0; q < 8; ++q) s += part[tid][q];
        h_s[tid] = tanhf(s);
    }
    __syncthreads();
    if (tid < C_ID) {
        float s = ldf(b2, tid, isf);
        #pragma unroll
        for (int i = 0; i < C_ID; ++i) s += h_s[i] * ldf(W2, tid * C_ID + i, isf);
        stf(d_out, b * C_ID + tid, tanhf(s), isf);
    }
}

extern "C" void kernel_launch(void* const* d_in, const int* in_sizes, int n_in,
                              void* d_out, int out_size, void* d_ws, size_t ws_size,
                              hipStream_t stream)
{
    const int* user_reviews = (const int*)d_in[0];
    const int* item_reviews = (const int*)d_in[1];
    const int* uids         = (const int*)d_in[2];
    const int* iids         = (const int*)d_in[3];
    const int* user2item    = (const int*)d_in[4];
    const int* item2user    = (const int*)d_in[5];
    const int* rand_reviews = (const int*)d_in[6];
    const void* user_emb = d_in[7];
    const void* item_emb = d_in[8];
    const void* cu_Wc = d_in[9];
    const void* cu_bc = d_in[10];
    const void* cu_Wl = d_in[11];
    const void* cu_bl = d_in[12];
    const void* ci_Wc = d_in[13];
    const void* ci_bc = d_in[14];
    const void* ci_Wl = d_in[15];
    const void* ci_bl = d_in[16];
    const void* t_W1  = d_in[17];
    const void* t_b1  = d_in[18];
    const void* t_W2  = d_in[19];
    const void* t_b2  = d_in[20];
    // d_in[21..23]: fs_* — outputs unused
    const void* te_emb = d_in[24];
    const void* tc_Wc  = d_in[25];
    const void* tc_bc  = d_in[26];
    const void* tc_Wl  = d_in[27];
    const void* tc_bl  = d_in[28];
    // d_in[29..31]: ft_* — unused

    u16*   ws_B   = (u16*)d_ws;                                 // 129024 B
    float* ws_cat = (float*)((char*)d_ws + 129536);             // 128*640 f32

    prep_bfrags<<<32, 256, 0, stream>>>(cu_Wc, ci_Wc, tc_Wc,
                                        (const u32*)user_emb, ws_B);

    cnn_mfma<<<2 * C_B * C_R + C_B, 256, 0, stream>>>(
        user_reviews, item_reviews, uids, iids, user2item, item2user, rand_reviews,
        user_emb, item_emb, te_emb,
        cu_bc, cu_Wl, cu_bl, ci_bc, ci_Wl, ci_bl, tc_bc, tc_Wl, tc_bl,
        ws_B, ws_cat, d_out);

    head_kernel<<<C_B, 256, 0, stream>>>(ws_cat, t_W1, t_b1, t_W2, t_b2,
                                         (const u32*)user_emb, d_out);
}

// Round 7
// 202.369 us; speedup vs baseline: 8.2823x; 1.0276x over previous
//
#include <hip/hip_runtime.h>
#include <hip/hip_bf16.h>

// TRANSNET on MI355X — round 7: global_load_lds staging (direct HBM->LDS,
// XOR-swizzled 128B rows), 4 blocks/CU, XCD-aware remap.
// Per review: GEMM M=256(L) x N=112(Fpad) x K=192 via mfma_f32_16x16x32_bf16
// in two N-passes; B-fragments pre-packed in global (L2-hot); LDS = emb only.

#define C_V 50000
#define C_D 64
#define C_F 100
#define C_K 3
#define C_L 256
#define C_R 10
#define C_ID 32
#define C_B 128

typedef unsigned int u32;
typedef unsigned short u16;
typedef __attribute__((ext_vector_type(8))) short bf16x8;
typedef __attribute__((ext_vector_type(4))) float f32x4;

__device__ __forceinline__ float bf2f(u16 h) { union {u32 u; float f;} v; v.u = ((u32)h) << 16; return v.f; }
__device__ __forceinline__ u16 f2bf(float f) {
    union {float f; u32 u;} v; v.f = f;
    u32 u = v.u;
    return (u16)((u + 0x7fffu + ((u >> 16) & 1u)) >> 16);  // RNE
}
__device__ __forceinline__ float ldf(const void* p, int idx, int isf) {
    return isf ? ((const float*)p)[idx] : bf2f(((const u16*)p)[idx]);
}
__device__ __forceinline__ void stf(void* p, int idx, float v, int isf) {
    if (isf) ((float*)p)[idx] = v; else ((u16*)p)[idx] = f2bf(v);
}
// Per-wave dtype probe: bf16 halves of N(0,0.1) values have exponent field in
// [0x70,0x7F]; f32 low-16 mantissa bits hit that window ~1/16 of the time.
__device__ __forceinline__ int detect_isf(const u32* __restrict__ ue, int lane) {
    u32 w = ue[lane];
    u32 e = (w >> 7) & 0xFFu;
    int hit = (e >= 0x70u && e <= 0x7Fu);
    unsigned long long m = __ballot(hit);
    return (__popcll(m) >= 32) ? 0 : 1;
}
// async global->LDS, 16B per lane; lds base must be wave-uniform.
__device__ __forceinline__ void gl_lds16(const void* g, void* l) {
    __builtin_amdgcn_global_load_lds(
        (const __attribute__((address_space(1))) void*)g,
        (__attribute__((address_space(3))) void*)l, 16, 0, 0);
}

// ---------------------------------------------------------------------------
// K0: pre-pack B fragments: [set(3)][c(6)][nt(7)][lane(64)][j(8)] bf16 —
// exactly the per-lane 16B the GEMM loads. f>=100 zero-padded.
// ---------------------------------------------------------------------------
__global__ __launch_bounds__(256) void prep_bfrags(
    const void* __restrict__ cu_Wc, const void* __restrict__ ci_Wc,
    const void* __restrict__ tc_Wc, const u32* __restrict__ ue,
    u16* __restrict__ wsB)
{
    int tid = threadIdx.x;
    int isf = detect_isf(ue, tid & 63);
    int id = blockIdx.x * 256 + tid;           // 3*6*7*64 = 8064 total
    if (id >= 3 * 6 * 7 * 64) return;
    int s    = id / 2688;
    int rem  = id % 2688;
    int c    = rem / 448;
    int rem2 = rem % 448;
    int nt   = rem2 / 64;
    int lane = rem2 % 64;
    int f    = nt * 16 + (lane & 15);
    int quad = lane >> 4;
    const void* W = (s == 0) ? cu_Wc : (s == 1) ? ci_Wc : tc_Wc;
    u16 out[8];
    #pragma unroll
    for (int j = 0; j < 8; ++j) {
        int kdim = c * 32 + quad * 8 + j;
        int tap = kdim >> 6, d = kdim & 63;
        float v = (f < C_F) ? ldf(W, (f * C_D + d) * C_K + tap, isf) : 0.f;
        out[j] = f2bf(v);
    }
    *reinterpret_cast<uint4*>(wsB + id * 8) = *reinterpret_cast<const uint4*>(out);
}

// ---------------------------------------------------------------------------
// K1: one block (4 waves) per review (2688).
// embS: 258 rows x 64 bf16 (128 B), XOR-chunk swizzle: 16B chunk c of row r
// lives in slot c^(r&7). Staged via global_load_lds (8 rows/instr/wave).
// LDS total 34.6 KB -> 4 blocks/CU.
// ---------------------------------------------------------------------------
__global__ __launch_bounds__(256, 4) void cnn_mfma(
    const int* __restrict__ user_reviews, const int* __restrict__ item_reviews,
    const int* __restrict__ uids, const int* __restrict__ iids,
    const int* __restrict__ user2item, const int* __restrict__ item2user,
    const int* __restrict__ rand_reviews,
    const void* __restrict__ user_emb, const void* __restrict__ item_emb,
    const void* __restrict__ te_emb,
    const void* __restrict__ cu_bc, const void* __restrict__ cu_Wl, const void* __restrict__ cu_bl,
    const void* __restrict__ ci_bc, const void* __restrict__ ci_Wl, const void* __restrict__ ci_bl,
    const void* __restrict__ tc_bc, const void* __restrict__ tc_Wl, const void* __restrict__ tc_bl,
    const u16* __restrict__ wsB,
    float* __restrict__ ws_cat, void* __restrict__ d_out)
{
    __shared__ __align__(16) char smem[258 * 128 + 1600];
    u16*   embS  = (u16*)smem;                  // [258][64] bf16, swizzled
    float* poolS = (float*)(smem + 258 * 128);  // [100][4]
    float* partS = (float*)smem;                // reused after GEMM

    const int tid = threadIdx.x;
    // XCD-aware remap: round-robin dispatch -> contiguous review range per XCD.
    const int idx = (blockIdx.x & 7) * 336 + (blockIdx.x >> 3);
    const int lane = tid & 63, wave = tid >> 6;
    const int isf = detect_isf((const u32*)user_emb, lane);

    const int* toks;
    const void* emb;
    int set;
    const void *bc, *Wl, *bl;

    if (idx < C_B * C_R) {                         // user reviews
        toks = user_reviews + idx * C_L;
        emb = user_emb; set = 0;
        bc = cu_bc; Wl = cu_Wl; bl = cu_bl;
    } else if (idx < 2 * C_B * C_R) {              // item reviews
        int j = idx - C_B * C_R;
        toks = item_reviews + j * C_L;
        emb = item_emb; set = 1;
        bc = ci_bc; Wl = ci_Wl; bl = ci_bl;
    } else {                                       // target review (selected)
        int b = idx - 2 * C_B * C_R;
        const int* t_ = rand_reviews + b * C_L;
        int iid = iids[b];
        int uid = uids[b];
        int fu = -1, fi = -1;
        for (int r = C_R - 1; r >= 0; --r) {       // first match (argmax of bool)
            if (user2item[b * C_R + r] == iid) fu = r;
            if (item2user[b * C_R + r] == uid) fi = r;
        }
        if (fu >= 0)      t_ = user_reviews + (b * C_R + fu) * C_L;
        else if (fi >= 0) t_ = item_reviews + (b * C_R + fi) * C_L;
        toks = t_;
        emb = te_emb; set = 2;
        bc = tc_bc; Wl = tc_Wl; bl = tc_bl;
    }

    // zero pad rows 0 (pos -1) and 257 (pos 256): 32 u32 each
    if (tid < 32)            ((u32*)embS)[tid] = 0u;
    else if (tid < 64)       ((u32*)embS)[257 * 32 + (tid - 32)] = 0u;

    // ---- stage embedding rows ----
    if (!isf) {
        // bf16 fast path: wave w stages rows [w*64, w*64+64) via 8
        // global_load_lds dwordx4: instr i covers 8 rows; lane -> row
        // w*64+i*8+(lane>>3), chunk slot lane&7, source chunk swizzled.
        int tok64 = toks[wave * 64 + lane];
        const u16* ebp = (const u16*)emb;
        #pragma unroll
        for (int i = 0; i < 8; ++i) {
            int sub = lane >> 3;                       // row within batch
            int token = __shfl(tok64, i * 8 + sub);
            int row_lds = wave * 64 + i * 8 + sub + 1;
            int schunk = (lane & 7) ^ (row_lds & 7);
            const void* g = ebp + (size_t)token * C_D + schunk * 8;
            u16* ldsbase = embS + (size_t)(wave * 64 + i * 8 + 1) * 64; // uniform
            gl_lds16(g, ldsbase);
        }
    } else {
        // f32 fallback: per-thread row, convert, store with same swizzle
        int token = toks[tid];
        int rw = (tid + 1) & 7;
        u16* dst = embS + (size_t)(tid + 1) * 64;
        const float4* srow = reinterpret_cast<const float4*>(
            (const float*)emb + (size_t)token * C_D);
        #pragma unroll
        for (int c = 0; c < 8; ++c) {
            float4 a = srow[2 * c];
            float4 b = srow[2 * c + 1];
            u16 t[8] = {f2bf(a.x), f2bf(a.y), f2bf(a.z), f2bf(a.w),
                        f2bf(b.x), f2bf(b.y), f2bf(b.z), f2bf(b.w)};
            *reinterpret_cast<uint4*>(dst + (c ^ rw) * 8) =
                *reinterpret_cast<const uint4*>(t);
        }
    }
    __syncthreads();

    const int quad = lane >> 4, mcol = lane & 15;
    const int mbase = wave * 64;
    const u16* BfG = wsB + set * 21504;   // this set's fragments

    // ---- pass 0: nt 0..3 (f 0..63) ----
    {
        f32x4 acc[4][4];
        #pragma unroll
        for (int mt = 0; mt < 4; ++mt)
            #pragma unroll
            for (int nt = 0; nt < 4; ++nt) acc[mt][nt] = (f32x4){0.f,0.f,0.f,0.f};
        #pragma unroll
        for (int c = 0; c < 6; ++c) {
            const int tap = c >> 1, dh = c & 1;
            // swizzled chunk slot: uniform over mt (mt*16 % 8 == 0)
            const int schunk = (dh * 4 + quad) ^ ((mcol + tap) & 7);
            bf16x8 bfr[4];
            #pragma unroll
            for (int nt = 0; nt < 4; ++nt)
                bfr[nt] = *reinterpret_cast<const bf16x8*>(BfG + ((c * 7 + nt) * 64 + lane) * 8);
            bf16x8 afr[4];
            #pragma unroll
            for (int mt = 0; mt < 4; ++mt) {
                int row = mbase + mt * 16 + mcol + tap;   // lds row (= pos + tap, pad-shifted)
                afr[mt] = *reinterpret_cast<const bf16x8*>(embS + row * 64 + schunk * 8);
            }
            #pragma unroll
            for (int mt = 0; mt < 4; ++mt)
                #pragma unroll
                for (int nt = 0; nt < 4; ++nt)
                    acc[mt][nt] = __builtin_amdgcn_mfma_f32_16x16x32_bf16(
                        afr[mt], bfr[nt], acc[mt][nt], 0, 0, 0);
        }
        #pragma unroll
        for (int nt = 0; nt < 4; ++nt) {
            float mv = -1e30f;
            #pragma unroll
            for (int mt = 0; mt < 4; ++mt)
                mv = fmaxf(mv, fmaxf(fmaxf(acc[mt][nt].x, acc[mt][nt].y),
                                     fmaxf(acc[mt][nt].z, acc[mt][nt].w)));
            mv = fmaxf(mv, __shfl_xor(mv, 16));
            mv = fmaxf(mv, __shfl_xor(mv, 32));
            if (quad == 0) poolS[(nt * 16 + mcol) * 4 + wave] = mv;   // f<=63<100
        }
    }
    // ---- pass 1: nt 4..6 (f 64..111, pad-zeros beyond 99) ----
    {
        f32x4 acc[4][3];
        #pragma unroll
        for (int mt = 0; mt < 4; ++mt)
            #pragma unroll
            for (int nt = 0; nt < 3; ++nt) acc[mt][nt] = (f32x4){0.f,0.f,0.f,0.f};
        #pragma unroll
        for (int c = 0; c < 6; ++c) {
            const int tap = c >> 1, dh = c & 1;
            const int schunk = (dh * 4 + quad) ^ ((mcol + tap) & 7);
            bf16x8 bfr[3];
            #pragma unroll
            for (int nt = 0; nt < 3; ++nt)
                bfr[nt] = *reinterpret_cast<const bf16x8*>(BfG + ((c * 7 + 4 + nt) * 64 + lane) * 8);
            bf16x8 afr[4];
            #pragma unroll
            for (int mt = 0; mt < 4; ++mt) {
                int row = mbase + mt * 16 + mcol + tap;
                afr[mt] = *reinterpret_cast<const bf16x8*>(embS + row * 64 + schunk * 8);
            }
            #pragma unroll
            for (int mt = 0; mt < 4; ++mt)
                #pragma unroll
                for (int nt = 0; nt < 3; ++nt)
                    acc[mt][nt] = __builtin_amdgcn_mfma_f32_16x16x32_bf16(
                        afr[mt], bfr[nt], acc[mt][nt], 0, 0, 0);
        }
        #pragma unroll
        for (int nt = 0; nt < 3; ++nt) {
            float mv = -1e30f;
            #pragma unroll
            for (int mt = 0; mt < 4; ++mt)
                mv = fmaxf(mv, fmaxf(fmaxf(acc[mt][nt].x, acc[mt][nt].y),
                                     fmaxf(acc[mt][nt].z, acc[mt][nt].w)));
            mv = fmaxf(mv, __shfl_xor(mv, 16));
            mv = fmaxf(mv, __shfl_xor(mv, 32));
            int f = (4 + nt) * 16 + mcol;
            if (quad == 0 && f < C_F) poolS[f * 4 + wave] = mv;
        }
    }
    __syncthreads();

    // cross-wave max + bias + relu -> poolS[f*4]
    if (tid < C_F) {
        float m4 = fmaxf(fmaxf(poolS[tid * 4 + 0], poolS[tid * 4 + 1]),
                         fmaxf(poolS[tid * 4 + 2], poolS[tid * 4 + 3]));
        poolS[tid * 4] = fmaxf(m4 + ldf(bc, tid, isf), 0.f);
    }
    __syncthreads();

    // wide linear F->ID: 8 threads per output, 12-13 f each
    {
        int o = tid >> 3, seg = tid & 7;
        int f0 = (seg < 4) ? seg * 13 : 52 + (seg - 4) * 12;
        int cnt = (seg < 4) ? 13 : 12;
        float acc = 0.f;
        for (int q = 0; q < cnt; ++q) {
            int f = f0 + q;
            acc += poolS[f * 4] * ldf(Wl, o * C_F + f, isf);
        }
        partS[o * 8 + seg] = acc;
    }
    __syncthreads();
    if (tid < C_ID) {
        float s = ldf(bl, tid, isf);
        #pragma unroll
        for (int q = 0; q < 8; ++q) s += partS[tid * 8 + q];
        float v = tanhf(s);
        if (idx < C_B * C_R) {
            int b = idx / C_R, r = idx % C_R;
            ws_cat[b * 640 + r * C_ID + tid] = v;
        } else if (idx < 2 * C_B * C_R) {
            int j = idx - C_B * C_R;
            int b = j / C_R, r = j % C_R;
            ws_cat[b * 640 + 320 + r * C_ID + tid] = v;
        } else {
            int b = idx - 2 * C_B * C_R;
            stf(d_out, C_B * C_ID + b * C_ID + tid, v, isf);   // tl after src
        }
    }
}

// ---------------------------------------------------------------------------
// K2: src head: h = tanh(cat @ W1^T + b1); src = tanh(h @ W2^T + b2).
// ---------------------------------------------------------------------------
__global__ __launch_bounds__(256) void head_kernel(
    const float* __restrict__ ws_cat,
    const void* __restrict__ W1, const void* __restrict__ b1,
    const void* __restrict__ W2, const void* __restrict__ b2,
    const u32* __restrict__ ue, void* __restrict__ d_out)
{
    __shared__ float part[C_ID][8];
    __shared__ float h_s[C_ID];
    int b = blockIdx.x;
    int tid = threadIdx.x;
    int isf = detect_isf(ue, tid & 63);
    int o = tid >> 3, seg = tid & 7;
    const float* cat = ws_cat + b * 640;
    float acc = 0.f;
    int j0 = seg * 80;
    for (int j = j0; j < j0 + 80; ++j) acc += cat[j] * ldf(W1, o * 640 + j, isf);
    part[o][seg] = acc;
    __syncthreads();
    if (tid < C_ID) {
        float s = ldf(b1, tid, isf);
        #pragma unroll
        for (int q = 0; q < 8; ++q) s += part[tid][q];
        h_s[tid] = tanhf(s);
    }
    __syncthreads();
    if (tid < C_ID) {
        float s = ldf(b2, tid, isf);
        #pragma unroll
        for (int i = 0; i < C_ID; ++i) s += h_s[i] * ldf(W2, tid * C_ID + i, isf);
        stf(d_out, b * C_ID + tid, tanhf(s), isf);
    }
}

extern "C" void kernel_launch(void* const* d_in, const int* in_sizes, int n_in,
                              void* d_out, int out_size, void* d_ws, size_t ws_size,
                              hipStream_t stream)
{
    const int* user_reviews = (const int*)d_in[0];
    const int* item_reviews = (const int*)d_in[1];
    const int* uids         = (const int*)d_in[2];
    const int* iids         = (const int*)d_in[3];
    const int* user2item    = (const int*)d_in[4];
    const int* item2user    = (const int*)d_in[5];
    const int* rand_reviews = (const int*)d_in[6];
    const void* user_emb = d_in[7];
    const void* item_emb = d_in[8];
    const void* cu_Wc = d_in[9];
    const void* cu_bc = d_in[10];
    const void* cu_Wl = d_in[11];
    const void* cu_bl = d_in[12];
    const void* ci_Wc = d_in[13];
    const void* ci_bc = d_in[14];
    const void* ci_Wl = d_in[15];
    const void* ci_bl = d_in[16];
    const void* t_W1  = d_in[17];
    const void* t_b1  = d_in[18];
    const void* t_W2  = d_in[19];
    const void* t_b2  = d_in[20];
    // d_in[21..23]: fs_* — outputs unused
    const void* te_emb = d_in[24];
    const void* tc_Wc  = d_in[25];
    const void* tc_bc  = d_in[26];
    const void* tc_Wl  = d_in[27];
    const void* tc_bl  = d_in[28];
    // d_in[29..31]: ft_* — unused

    u16*   ws_B   = (u16*)d_ws;                                 // 129024 B
    float* ws_cat = (float*)((char*)d_ws + 129536);             // 128*640 f32

    prep_bfrags<<<32, 256, 0, stream>>>(cu_Wc, ci_Wc, tc_Wc,
                                        (const u32*)user_emb, ws_B);

    cnn_mfma<<<2 * C_B * C_R + C_B, 256, 0, stream>>>(
        user_reviews, item_reviews, uids, iids, user2item, item2user, rand_reviews,
        user_emb, item_emb, te_emb,
        cu_bc, cu_Wl, cu_bl, ci_bc, ci_Wl, ci_bl, tc_bc, tc_Wl, tc_bl,
        ws_B, ws_cat, d_out);

    head_kernel<<<C_B, 256, 0, stream>>>(ws_cat, t_W1, t_b1, t_W2, t_b2,
                                         (const u32*)user_emb, d_out);
}